// Round 4
// baseline (223.322 us; speedup 1.0000x reference)
//
#include <hip/hip_runtime.h>
#include <stdint.h>

#define NROWS 8192
#define DIM 128

typedef __bf16 bf16x8 __attribute__((ext_vector_type(8)));
typedef float floatx4 __attribute__((ext_vector_type(4)));

// ---------- helpers ----------
static __device__ __forceinline__ unsigned short f2bf(float f) {
    unsigned int u = __float_as_uint(f);
    unsigned int r = (u + 0x7FFFu + ((u >> 16) & 1u)) >> 16;   // RNE
    return (unsigned short)r;
}

// XOR swizzle on linear uint4 index g (cols x 16 uint4 per col):
// breaks the 16-way bank-group conflict of the naive layout; swizzled
// access is balanced across bank groups (2-way = free, m136).
static __device__ __forceinline__ int swz(int g) {
    return (g & ~15) | ((g & 15) ^ ((g >> 4) & 7));
}

// ---------- kernel 1: normalize rows, emit bf16 a_hat + pos_dist + init max keys ----------
__global__ __launch_bounds__(256) void normalize_kernel(
    const float* __restrict__ anchor, const float* __restrict__ positive,
    unsigned short* __restrict__ a_hat, float* __restrict__ pos_ws,
    int* __restrict__ g_ws)
{
    const int wave = threadIdx.x >> 6;
    const int lane = threadIdx.x & 63;
    const int row  = blockIdx.x * 4 + wave;

    const float2* arow = (const float2*)(anchor   + row * DIM);
    const float2* prow = (const float2*)(positive + row * DIM);
    float2 a = arow[lane];
    float2 p = prow[lane];

    float sa  = a.x * a.x + a.y * a.y;
    float sp  = p.x * p.x + p.y * p.y;
    float sap = a.x * p.x + a.y * p.y;
    #pragma unroll
    for (int off = 32; off; off >>= 1) {
        sa  += __shfl_xor(sa,  off);
        sp  += __shfl_xor(sp,  off);
        sap += __shfl_xor(sap, off);
    }
    float na  = fmaxf(sqrtf(sa), 1e-12f);
    float npn = fmaxf(sqrtf(sp), 1e-12f);
    float inv = 1.0f / na;

    ushort2 pack;
    pack.x = f2bf(a.x * inv);
    pack.y = f2bf(a.y * inv);
    ((ushort2*)a_hat)[row * 64 + lane] = pack;

    if (lane == 0) {
        pos_ws[row] = 2.0f - 2.0f * sap / (na * npn);
        g_ws[row]   = 0x3F800000;   // key for g = -1  (key = 2+g = 1.0f)
    }
}

// ---------- kernel 2: fused gram row-max, barrier-free K-loop ----------
// grid = 1024: blockIdx>>4 = colBlock (128 cols), blockIdx&15 = rowSplit
// (512 rows). B-chunk (128 cols x 128 dim = 32 KB) pinned in swizzled LDS
// once (single barrier); col labels in 8 regs. Each wave streams 128 rows
// as 2 strips of 64 (afrag[4][4]) from L2 — no barriers, no shared-buffer
// hazards, waves run free.
__global__ __launch_bounds__(256, 3) void gram_kernel(
    const unsigned short* __restrict__ a_hat, const int* __restrict__ labels,
    int* __restrict__ g_ws)
{
    const int tid  = threadIdx.x;
    const int lane = tid & 63;
    const int wave = tid >> 6;
    const int quad = lane >> 4;
    const int l15  = lane & 15;

    const int colBlock = blockIdx.x >> 4;     // 0..63
    const int rowSplit = blockIdx.x & 15;     // 0..15
    const int colBase  = colBlock * 128;
    const int rowBase0 = rowSplit * 512 + wave * 128;

    const uint4* A = (const uint4*)a_hat;     // row stride = 16 uint4 (256 B)

    __shared__ uint4 smem[2048];              // 32 KB: 128 cols x 16 uint4

    // ---- stage B-chunk once (8 uint4 per thread), swizzled ----
    const uint4* Bp = A + colBase * 16;
    #pragma unroll
    for (int t = 0; t < 8; ++t) {
        int g = t * 256 + tid;
        smem[swz(g)] = Bp[g];
    }

    // col labels: 8 regs (ns-tile layout: col = ns*16 + l15)
    int clab[8];
    #pragma unroll
    for (int ns = 0; ns < 8; ++ns)
        clab[ns] = labels[colBase + ns * 16 + l15];

    __syncthreads();                          // the only barrier

    // ---- stream 2 strips of 64 rows ----
    for (int s64 = 0; s64 < 2; ++s64) {
        const int rowBase = rowBase0 + s64 * 64;

        // A fragments: lane holds A[m=l15][k = quad*8..+7] (+32 per kstep)
        bf16x8 afrag[4][4];
        #pragma unroll
        for (int s = 0; s < 4; ++s) {
            int r = rowBase + s * 16 + l15;
            #pragma unroll
            for (int k = 0; k < 4; ++k) {
                uint4 v = A[r * 16 + k * 4 + quad];
                afrag[s][k] = __builtin_bit_cast(bf16x8, v);
            }
        }

        // row labels for this lane's C rows: row = rowBase + s*16 + quad*4 + e
        int rlab[4][4];
        #pragma unroll
        for (int s = 0; s < 4; ++s)
            #pragma unroll
            for (int e = 0; e < 4; ++e)
                rlab[s][e] = labels[rowBase + s * 16 + quad * 4 + e];

        float gmax[4][4];
        #pragma unroll
        for (int s = 0; s < 4; ++s)
            #pragma unroll
            for (int e = 0; e < 4; ++e)
                gmax[s][e] = -4.0f;

        #pragma unroll
        for (int ns = 0; ns < 8; ++ns) {
            bf16x8 bfrag[4];
            #pragma unroll
            for (int k = 0; k < 4; ++k) {
                int g = (ns * 16 + l15) * 16 + k * 4 + quad;
                bfrag[k] = __builtin_bit_cast(bf16x8, smem[swz(g)]);
            }
            const int cl = clab[ns];
            #pragma unroll
            for (int ms = 0; ms < 4; ++ms) {
                floatx4 acc = {0.f, 0.f, 0.f, 0.f};
                #pragma unroll
                for (int k = 0; k < 4; ++k)
                    acc = __builtin_amdgcn_mfma_f32_16x16x32_bf16(
                              afrag[ms][k], bfrag[k], acc, 0, 0, 0);
                #pragma unroll
                for (int e = 0; e < 4; ++e) {
                    float v = (cl != rlab[ms][e]) ? acc[e] : -4.0f;
                    gmax[ms][e] = fmaxf(gmax[ms][e], v);
                }
            }
        }

        // reduce cols over the 16 lanes of each quad, then atomicMax per row
        #pragma unroll
        for (int s = 0; s < 4; ++s) {
            #pragma unroll
            for (int e = 0; e < 4; ++e) {
                float v = gmax[s][e];
                #pragma unroll
                for (int off = 1; off < 16; off <<= 1)
                    v = fmaxf(v, __shfl_xor(v, off));
                if (l15 == 0) {
                    int r = rowBase + s * 16 + quad * 4 + e;
                    atomicMax(g_ws + r, __float_as_int(2.0f + v));  // keys > 0
                }
            }
        }
    }
}

// ---------- kernel 3: final loss + mean ----------
__global__ __launch_bounds__(256) void loss_kernel(
    const float* __restrict__ pos_ws, const int* __restrict__ g_ws,
    float* __restrict__ out)
{
    const int i = blockIdx.x * 256 + threadIdx.x;
    float g    = __int_as_float(g_ws[i]) - 2.0f;
    float neg  = fmaxf(2.0f - 2.0f * g, 0.0f);
    float loss = fmaxf(pos_ws[i] - neg + 0.5f, 0.0f);

    #pragma unroll
    for (int off = 32; off; off >>= 1)
        loss += __shfl_xor(loss, off);

    __shared__ float ws[4];
    if ((threadIdx.x & 63) == 0) ws[threadIdx.x >> 6] = loss;
    __syncthreads();
    if (threadIdx.x == 0) {
        float s = ws[0] + ws[1] + ws[2] + ws[3];
        atomicAdd(out, s * (1.0f / 8192.0f));
    }
}

extern "C" void kernel_launch(void* const* d_in, const int* in_sizes, int n_in,
                              void* d_out, int out_size, void* d_ws, size_t ws_size,
                              hipStream_t stream) {
    const float* anchor   = (const float*)d_in[0];
    const float* positive = (const float*)d_in[1];
    const int*   labels   = (const int*)d_in[2];
    float* out = (float*)d_out;

    char* ws = (char*)d_ws;
    unsigned short* a_hat  = (unsigned short*)ws;                       // 2 MiB
    float*          pos_ws = (float*)(ws + 2 * 1024 * 1024);            // 32 KiB
    int*            g_ws   = (int*)  (ws + 2 * 1024 * 1024 + 32 * 1024);// 32 KiB

    hipMemsetAsync(d_out, 0, sizeof(float), stream);
    normalize_kernel<<<NROWS / 4, 256, 0, stream>>>(anchor, positive, a_hat, pos_ws, g_ws);
    gram_kernel<<<1024, 256, 0, stream>>>(a_hat, labels, g_ws);
    loss_kernel<<<NROWS / 256, 256, 0, stream>>>(pos_ws, g_ws, out);
}

// Round 5
// 167.220 us; speedup vs baseline: 1.3355x; 1.3355x over previous
//
#include <hip/hip_runtime.h>
#include <stdint.h>

#define NROWS 8192
#define DIM 128

typedef __bf16 bf16x8 __attribute__((ext_vector_type(8)));
typedef float floatx4 __attribute__((ext_vector_type(4)));

// ---------- helpers ----------
static __device__ __forceinline__ unsigned short f2bf(float f) {
    unsigned int u = __float_as_uint(f);
    unsigned int r = (u + 0x7FFFu + ((u >> 16) & 1u)) >> 16;   // RNE
    return (unsigned short)r;
}

// XOR swizzle on linear uint4 index g (cols x 16 uint4 per col):
// balances ds_read_b128 bank-group access (2-way = free, m136).
static __device__ __forceinline__ int swz(int g) {
    return (g & ~15) | ((g & 15) ^ ((g >> 4) & 7));
}

// ---------- kernel 1: normalize rows, emit bf16 a_hat + pos_dist + init max keys ----------
__global__ __launch_bounds__(256) void normalize_kernel(
    const float* __restrict__ anchor, const float* __restrict__ positive,
    unsigned short* __restrict__ a_hat, float* __restrict__ pos_ws,
    int* __restrict__ g_ws)
{
    const int wave = threadIdx.x >> 6;
    const int lane = threadIdx.x & 63;
    const int row  = blockIdx.x * 4 + wave;

    const float2* arow = (const float2*)(anchor   + row * DIM);
    const float2* prow = (const float2*)(positive + row * DIM);
    float2 a = arow[lane];
    float2 p = prow[lane];

    float sa  = a.x * a.x + a.y * a.y;
    float sp  = p.x * p.x + p.y * p.y;
    float sap = a.x * p.x + a.y * p.y;
    #pragma unroll
    for (int off = 32; off; off >>= 1) {
        sa  += __shfl_xor(sa,  off);
        sp  += __shfl_xor(sp,  off);
        sap += __shfl_xor(sap, off);
    }
    float na  = fmaxf(sqrtf(sa), 1e-12f);
    float npn = fmaxf(sqrtf(sp), 1e-12f);
    float inv = 1.0f / na;

    ushort2 pack;
    pack.x = f2bf(a.x * inv);
    pack.y = f2bf(a.y * inv);
    ((ushort2*)a_hat)[row * 64 + lane] = pack;

    if (lane == 0) {
        pos_ws[row] = 2.0f - 2.0f * sap / (na * npn);
        g_ws[row]   = 0x3F800000;   // key for g = -1  (key = 2+g = 1.0f)
    }
}

// ---------- kernel 2: fused gram row-max, barrier-free K-loop ----------
// grid = 1024: blockIdx>>4 = colBlock (128 cols), blockIdx&15 = rowSplit
// (512 rows). B-chunk (128 cols x 128 dim = 32 KB) pinned in swizzled LDS
// once (single barrier); col labels in 8 regs. Each wave streams 128 rows
// as 2 strips of 64 (afrag[4][4]) from L2 — no K-loop barriers.
// launch_bounds(256,2): VGPR cap 256 — (256,3)'s 170-cap forced scratch
// spills (R4: 355 MB WRITE_SIZE, 84 VGPR) which thrashed L2 and made the
// kernel spill-traffic-bound. Do NOT tighten this.
__global__ __launch_bounds__(256, 2) void gram_kernel(
    const unsigned short* __restrict__ a_hat, const int* __restrict__ labels,
    int* __restrict__ g_ws)
{
    const int tid  = threadIdx.x;
    const int lane = tid & 63;
    const int wave = tid >> 6;
    const int quad = lane >> 4;
    const int l15  = lane & 15;

    const int colBlock = blockIdx.x >> 4;     // 0..63
    const int rowSplit = blockIdx.x & 15;     // 0..15
    const int colBase  = colBlock * 128;
    const int rowBase0 = rowSplit * 512 + wave * 128;

    const uint4* A = (const uint4*)a_hat;     // row stride = 16 uint4 (256 B)

    __shared__ uint4 smem[2048];              // 32 KB: 128 cols x 16 uint4

    // ---- stage B-chunk once (8 uint4 per thread), swizzled ----
    const uint4* Bp = A + colBase * 16;
    #pragma unroll
    for (int t = 0; t < 8; ++t) {
        int g = t * 256 + tid;
        smem[swz(g)] = Bp[g];
    }

    // col labels: 8 regs (ns-tile layout: col = ns*16 + l15)
    int clab[8];
    #pragma unroll
    for (int ns = 0; ns < 8; ++ns)
        clab[ns] = labels[colBase + ns * 16 + l15];

    __syncthreads();                          // the only barrier

    // ---- stream 2 strips of 64 rows ----
    for (int s64 = 0; s64 < 2; ++s64) {
        const int rowBase = rowBase0 + s64 * 64;

        // A fragments: lane holds A[m=l15][k = quad*8..+7] (+32 per kstep)
        bf16x8 afrag[4][4];
        #pragma unroll
        for (int s = 0; s < 4; ++s) {
            int r = rowBase + s * 16 + l15;
            #pragma unroll
            for (int k = 0; k < 4; ++k) {
                uint4 v = A[r * 16 + k * 4 + quad];
                afrag[s][k] = __builtin_bit_cast(bf16x8, v);
            }
        }

        // row labels for this lane's C rows: row = rowBase + s*16 + quad*4 + e
        int rlab[4][4];
        #pragma unroll
        for (int s = 0; s < 4; ++s)
            #pragma unroll
            for (int e = 0; e < 4; ++e)
                rlab[s][e] = labels[rowBase + s * 16 + quad * 4 + e];

        float gmax[4][4];
        #pragma unroll
        for (int s = 0; s < 4; ++s)
            #pragma unroll
            for (int e = 0; e < 4; ++e)
                gmax[s][e] = -4.0f;

        #pragma unroll
        for (int ns = 0; ns < 8; ++ns) {
            bf16x8 bfrag[4];
            #pragma unroll
            for (int k = 0; k < 4; ++k) {
                int g = (ns * 16 + l15) * 16 + k * 4 + quad;
                bfrag[k] = __builtin_bit_cast(bf16x8, smem[swz(g)]);
            }
            const int cl = clab[ns];
            #pragma unroll
            for (int ms = 0; ms < 4; ++ms) {
                floatx4 acc = {0.f, 0.f, 0.f, 0.f};
                #pragma unroll
                for (int k = 0; k < 4; ++k)
                    acc = __builtin_amdgcn_mfma_f32_16x16x32_bf16(
                              afrag[ms][k], bfrag[k], acc, 0, 0, 0);
                #pragma unroll
                for (int e = 0; e < 4; ++e) {
                    float v = (cl != rlab[ms][e]) ? acc[e] : -4.0f;
                    gmax[ms][e] = fmaxf(gmax[ms][e], v);
                }
            }
        }

        // reduce cols over the 16 lanes of each quad, then atomicMax per row
        #pragma unroll
        for (int s = 0; s < 4; ++s) {
            #pragma unroll
            for (int e = 0; e < 4; ++e) {
                float v = gmax[s][e];
                #pragma unroll
                for (int off = 1; off < 16; off <<= 1)
                    v = fmaxf(v, __shfl_xor(v, off));
                if (l15 == 0) {
                    int r = rowBase + s * 16 + quad * 4 + e;
                    atomicMax(g_ws + r, __float_as_int(2.0f + v));  // keys > 0
                }
            }
        }
    }
}

// ---------- kernel 3: final loss + mean ----------
__global__ __launch_bounds__(256) void loss_kernel(
    const float* __restrict__ pos_ws, const int* __restrict__ g_ws,
    float* __restrict__ out)
{
    const int i = blockIdx.x * 256 + threadIdx.x;
    float g    = __int_as_float(g_ws[i]) - 2.0f;
    float neg  = fmaxf(2.0f - 2.0f * g, 0.0f);
    float loss = fmaxf(pos_ws[i] - neg + 0.5f, 0.0f);

    #pragma unroll
    for (int off = 32; off; off >>= 1)
        loss += __shfl_xor(loss, off);

    __shared__ float ws[4];
    if ((threadIdx.x & 63) == 0) ws[threadIdx.x >> 6] = loss;
    __syncthreads();
    if (threadIdx.x == 0) {
        float s = ws[0] + ws[1] + ws[2] + ws[3];
        atomicAdd(out, s * (1.0f / 8192.0f));
    }
}

extern "C" void kernel_launch(void* const* d_in, const int* in_sizes, int n_in,
                              void* d_out, int out_size, void* d_ws, size_t ws_size,
                              hipStream_t stream) {
    const float* anchor   = (const float*)d_in[0];
    const float* positive = (const float*)d_in[1];
    const int*   labels   = (const int*)d_in[2];
    float* out = (float*)d_out;

    char* ws = (char*)d_ws;
    unsigned short* a_hat  = (unsigned short*)ws;                       // 2 MiB
    float*          pos_ws = (float*)(ws + 2 * 1024 * 1024);            // 32 KiB
    int*            g_ws   = (int*)  (ws + 2 * 1024 * 1024 + 32 * 1024);// 32 KiB

    hipMemsetAsync(d_out, 0, sizeof(float), stream);
    normalize_kernel<<<NROWS / 4, 256, 0, stream>>>(anchor, positive, a_hat, pos_ws, g_ws);
    gram_kernel<<<1024, 256, 0, stream>>>(a_hat, labels, g_ws);
    loss_kernel<<<NROWS / 256, 256, 0, stream>>>(pos_ws, g_ws, out);
}

// Round 6
// 133.940 us; speedup vs baseline: 1.6673x; 1.2485x over previous
//
#include <hip/hip_runtime.h>
#include <stdint.h>

#define NROWS 8192
#define DIM 128

typedef __bf16 bf16x8 __attribute__((ext_vector_type(8)));
typedef float floatx4 __attribute__((ext_vector_type(4)));

// ---------- helpers ----------
static __device__ __forceinline__ unsigned short f2bf(float f) {
    unsigned int u = __float_as_uint(f);
    unsigned int r = (u + 0x7FFFu + ((u >> 16) & 1u)) >> 16;   // RNE
    return (unsigned short)r;
}

// ---------- kernel 1: normalize rows, emit bf16 a_hat + pos_dist + init max keys ----------
__global__ __launch_bounds__(256) void normalize_kernel(
    const float* __restrict__ anchor, const float* __restrict__ positive,
    unsigned short* __restrict__ a_hat, float* __restrict__ pos_ws,
    int* __restrict__ g_ws)
{
    const int wave = threadIdx.x >> 6;
    const int lane = threadIdx.x & 63;
    const int row  = blockIdx.x * 4 + wave;

    const float2* arow = (const float2*)(anchor   + row * DIM);
    const float2* prow = (const float2*)(positive + row * DIM);
    float2 a = arow[lane];
    float2 p = prow[lane];

    float sa  = a.x * a.x + a.y * a.y;
    float sp  = p.x * p.x + p.y * p.y;
    float sap = a.x * p.x + a.y * p.y;
    #pragma unroll
    for (int off = 32; off; off >>= 1) {
        sa  += __shfl_xor(sa,  off);
        sp  += __shfl_xor(sp,  off);
        sap += __shfl_xor(sap, off);
    }
    float na  = fmaxf(sqrtf(sa), 1e-12f);
    float npn = fmaxf(sqrtf(sp), 1e-12f);
    float inv = 1.0f / na;

    ushort2 pack;
    pack.x = f2bf(a.x * inv);
    pack.y = f2bf(a.y * inv);
    ((ushort2*)a_hat)[row * 64 + lane] = pack;

    if (lane == 0) {
        pos_ws[row] = 2.0f - 2.0f * sap / (na * npn);
        g_ws[row]   = 0x3F800000;   // key for g = -1  (key = 2+g = 1.0f)
    }
}

// ---------- kernel 2: fused gram row-max — no LDS, register ping-pong prefetch ----------
// grid = 2048: blockIdx&63 = rowBlock (128 rows), blockIdx>>6 = colChunk
// (256 cols). Wave strip = 32 rows (afrag[2][4]); 8 col-tiles of 32, tile
// t+1's 8 b128 loads issued before tile t's compute (ping-pong regs,
// unroll-2 so indices are static). The block's 4 waves walk the same
// B-tiles -> L1 reuse. NO __launch_bounds__ minimum: R4/R5 showed forcing
// occupancy makes the allocator spill (~190-355 MB scratch traffic, L2
// thrash). Let it pick; ~140 live VGPRs -> 3 waves/SIMD is fine.
__global__ __launch_bounds__(256) void gram_kernel(
    const unsigned short* __restrict__ a_hat, const int* __restrict__ labels,
    int* __restrict__ g_ws)
{
    const int lane = threadIdx.x & 63;
    const int wave = threadIdx.x >> 6;
    const int quad = lane >> 4;
    const int l15  = lane & 15;

    const int rowBlock = blockIdx.x & 63;     // 0..63 -> 128 rows
    const int colChunk = blockIdx.x >> 6;     // 0..31 -> 256 cols
    const int rowBase  = rowBlock * 128 + wave * 32;
    const int colBase  = colChunk * 256;

    const uint4* A = (const uint4*)a_hat;     // row stride = 16 uint4 (256 B)

    // A fragments: lane holds A[m=l15][k = quad*8..+7] (+32 per kstep)
    bf16x8 afrag[2][4];
    #pragma unroll
    for (int s = 0; s < 2; ++s) {
        int r = rowBase + s * 16 + l15;
        #pragma unroll
        for (int k = 0; k < 4; ++k) {
            uint4 v = A[r * 16 + k * 4 + quad];
            afrag[s][k] = __builtin_bit_cast(bf16x8, v);
        }
    }

    // row labels for this lane's C rows: row = rowBase + s*16 + quad*4 + e
    int rlab[2][4];
    #pragma unroll
    for (int s = 0; s < 2; ++s)
        #pragma unroll
        for (int e = 0; e < 4; ++e)
            rlab[s][e] = labels[rowBase + s * 16 + quad * 4 + e];

    // col labels for all 8 tiles, preloaded (keeps them off the K-loop path)
    int clab0[8], clab1[8];
    #pragma unroll
    for (int t = 0; t < 8; ++t) {
        clab0[t] = labels[colBase + t * 32 + l15];
        clab1[t] = labels[colBase + t * 32 + 16 + l15];
    }

    float gmax[2][4];
    #pragma unroll
    for (int s = 0; s < 2; ++s)
        #pragma unroll
        for (int e = 0; e < 4; ++e)
            gmax[s][e] = -4.0f;

    const uint4* Bp = A + colBase * 16;       // 256 cols x 16 uint4

    // ping-pong B fragments: bb[buf][ns][k]
    bf16x8 bb[2][2][4];
    #pragma unroll
    for (int ns = 0; ns < 2; ++ns) {
        int c = ns * 16 + l15;
        #pragma unroll
        for (int k = 0; k < 4; ++k)
            bb[0][ns][k] = __builtin_bit_cast(bf16x8, Bp[c * 16 + k * 4 + quad]);
    }

    #pragma unroll 2
    for (int t = 0; t < 8; ++t) {
        const int cur = t & 1, nxt = cur ^ 1;

        if (t < 7) {                          // prefetch tile t+1
            #pragma unroll
            for (int ns = 0; ns < 2; ++ns) {
                int c = (t + 1) * 32 + ns * 16 + l15;
                #pragma unroll
                for (int k = 0; k < 4; ++k)
                    bb[nxt][ns][k] =
                        __builtin_bit_cast(bf16x8, Bp[c * 16 + k * 4 + quad]);
            }
        }

        #pragma unroll
        for (int ns = 0; ns < 2; ++ns) {
            const int cl = ns ? clab1[t] : clab0[t];
            #pragma unroll
            for (int ms = 0; ms < 2; ++ms) {
                floatx4 acc = {0.f, 0.f, 0.f, 0.f};
                #pragma unroll
                for (int k = 0; k < 4; ++k)
                    acc = __builtin_amdgcn_mfma_f32_16x16x32_bf16(
                              afrag[ms][k], bb[cur][ns][k], acc, 0, 0, 0);
                #pragma unroll
                for (int e = 0; e < 4; ++e) {
                    float v = (cl != rlab[ms][e]) ? acc[e] : -4.0f;
                    gmax[ms][e] = fmaxf(gmax[ms][e], v);
                }
            }
        }
    }

    // reduce cols over the 16 lanes of each quad, then atomicMax per row
    #pragma unroll
    for (int s = 0; s < 2; ++s) {
        #pragma unroll
        for (int e = 0; e < 4; ++e) {
            float v = gmax[s][e];
            #pragma unroll
            for (int off = 1; off < 16; off <<= 1)
                v = fmaxf(v, __shfl_xor(v, off));
            if (l15 == 0) {
                int r = rowBase + s * 16 + quad * 4 + e;
                atomicMax(g_ws + r, __float_as_int(2.0f + v));  // keys > 0
            }
        }
    }
}

// ---------- kernel 3: final loss + mean ----------
__global__ __launch_bounds__(256) void loss_kernel(
    const float* __restrict__ pos_ws, const int* __restrict__ g_ws,
    float* __restrict__ out)
{
    const int i = blockIdx.x * 256 + threadIdx.x;
    float g    = __int_as_float(g_ws[i]) - 2.0f;
    float neg  = fmaxf(2.0f - 2.0f * g, 0.0f);
    float loss = fmaxf(pos_ws[i] - neg + 0.5f, 0.0f);

    #pragma unroll
    for (int off = 32; off; off >>= 1)
        loss += __shfl_xor(loss, off);

    __shared__ float ws[4];
    if ((threadIdx.x & 63) == 0) ws[threadIdx.x >> 6] = loss;
    __syncthreads();
    if (threadIdx.x == 0) {
        float s = ws[0] + ws[1] + ws[2] + ws[3];
        atomicAdd(out, s * (1.0f / 8192.0f));
    }
}

extern "C" void kernel_launch(void* const* d_in, const int* in_sizes, int n_in,
                              void* d_out, int out_size, void* d_ws, size_t ws_size,
                              hipStream_t stream) {
    const float* anchor   = (const float*)d_in[0];
    const float* positive = (const float*)d_in[1];
    const int*   labels   = (const int*)d_in[2];
    float* out = (float*)d_out;

    char* ws = (char*)d_ws;
    unsigned short* a_hat  = (unsigned short*)ws;                       // 2 MiB
    float*          pos_ws = (float*)(ws + 2 * 1024 * 1024);            // 32 KiB
    int*            g_ws   = (int*)  (ws + 2 * 1024 * 1024 + 32 * 1024);// 32 KiB

    hipMemsetAsync(d_out, 0, sizeof(float), stream);
    normalize_kernel<<<NROWS / 4, 256, 0, stream>>>(anchor, positive, a_hat, pos_ws, g_ws);
    gram_kernel<<<2048, 256, 0, stream>>>(a_hat, labels, g_ws);
    loss_kernel<<<NROWS / 256, 256, 0, stream>>>(pos_ws, g_ws, out);
}

// Round 7
// 106.221 us; speedup vs baseline: 2.1024x; 1.2610x over previous
//
#include <hip/hip_runtime.h>
#include <stdint.h>

#define NROWS 8192
#define DIM 128

typedef __bf16 bf16x8 __attribute__((ext_vector_type(8)));
typedef float floatx4 __attribute__((ext_vector_type(4)));

// ---------- helpers ----------
static __device__ __forceinline__ unsigned short f2bf(float f) {
    unsigned int u = __float_as_uint(f);
    unsigned int r = (u + 0x7FFFu + ((u >> 16) & 1u)) >> 16;   // RNE
    return (unsigned short)r;
}

// XOR swizzle on linear uint4 index g (cols x 16 uint4 per col):
// g>>4 = col, so low4 ^= col&7 spreads the 16 lanes of a ds_read_b128
// over 8 bank-groups (2-way = free, m136). Unswizzled, all 16 lanes of a
// bfrag read hit one 4-bank group (16-way serialization).
static __device__ __forceinline__ int swz(int g) {
    return (g & ~15) | ((g & 15) ^ ((g >> 4) & 7));
}

// ---------- kernel 1: normalize rows, emit bf16 a_hat + pos_dist + init max keys ----------
__global__ __launch_bounds__(256) void normalize_kernel(
    const float* __restrict__ anchor, const float* __restrict__ positive,
    unsigned short* __restrict__ a_hat, float* __restrict__ pos_ws,
    int* __restrict__ g_ws)
{
    const int wave = threadIdx.x >> 6;
    const int lane = threadIdx.x & 63;
    const int row  = blockIdx.x * 4 + wave;

    const float2* arow = (const float2*)(anchor   + row * DIM);
    const float2* prow = (const float2*)(positive + row * DIM);
    float2 a = arow[lane];
    float2 p = prow[lane];

    float sa  = a.x * a.x + a.y * a.y;
    float sp  = p.x * p.x + p.y * p.y;
    float sap = a.x * p.x + a.y * p.y;
    #pragma unroll
    for (int off = 32; off; off >>= 1) {
        sa  += __shfl_xor(sa,  off);
        sp  += __shfl_xor(sp,  off);
        sap += __shfl_xor(sap, off);
    }
    float na  = fmaxf(sqrtf(sa), 1e-12f);
    float npn = fmaxf(sqrtf(sp), 1e-12f);
    float inv = 1.0f / na;

    ushort2 pack;
    pack.x = f2bf(a.x * inv);
    pack.y = f2bf(a.y * inv);
    ((ushort2*)a_hat)[row * 64 + lane] = pack;

    if (lane == 0) {
        pos_ws[row] = 2.0f - 2.0f * sap / (na * npn);
        g_ws[row]   = 0x3F800000;   // key for g = -1  (key = 2+g = 1.0f)
    }
}

// ---------- kernel 2: fused gram row-max — B pinned in LDS, barrier-free K-loop ----------
// grid = 1024: blockIdx>>4 = colBlock (128 cols), blockIdx&15 = rowSplit
// (512 rows). B-chunk (128 cols x 128 dim = 32 KB) staged in swizzled LDS
// ONCE (single barrier per kernel). Each wave streams its 128 rows as 4
// strips of 32 (afrag[2][4] = 32 regs — NOT R5's 64: that structure made
// the allocator spill ~190 MB of scratch). Live regs ~95-110 < the
// allocator's 128 target -> no spill, 4 blocks/CU (LDS-capped), 16
// waves/CU hide the strip-start global latency.
__global__ __launch_bounds__(256, 2) void gram_kernel(
    const unsigned short* __restrict__ a_hat, const int* __restrict__ labels,
    int* __restrict__ g_ws)
{
    const int tid  = threadIdx.x;
    const int lane = tid & 63;
    const int wave = tid >> 6;
    const int quad = lane >> 4;
    const int l15  = lane & 15;

    const int colBlock = blockIdx.x >> 4;     // 0..63
    const int rowSplit = blockIdx.x & 15;     // 0..15
    const int colBase  = colBlock * 128;
    const int rowBase0 = rowSplit * 512 + wave * 128;

    const uint4* A = (const uint4*)a_hat;     // row stride = 16 uint4 (256 B)

    __shared__ uint4 smem[2048];              // 32 KB: 128 cols x 16 uint4

    // ---- stage B-chunk once (8 uint4 per thread), swizzled ----
    const uint4* Bp = A + colBase * 16;
    #pragma unroll
    for (int t = 0; t < 8; ++t) {
        int g = t * 256 + tid;
        smem[swz(g)] = Bp[g];
    }

    // col labels: 8 regs (tile t, subtile ns: col = t*32 + ns*16 + l15)
    int clab0[4], clab1[4];
    #pragma unroll
    for (int t = 0; t < 4; ++t) {
        clab0[t] = labels[colBase + t * 32 + l15];
        clab1[t] = labels[colBase + t * 32 + 16 + l15];
    }

    __syncthreads();                          // the only barrier

    // ---- stream 4 strips of 32 rows ----
    for (int siter = 0; siter < 4; ++siter) {
        const int rowBase = rowBase0 + siter * 32;

        // A fragments: lane holds A[m=l15][k = quad*8..+7] (+32 per kstep)
        bf16x8 afrag[2][4];
        #pragma unroll
        for (int s = 0; s < 2; ++s) {
            int r = rowBase + s * 16 + l15;
            #pragma unroll
            for (int k = 0; k < 4; ++k) {
                uint4 v = A[r * 16 + k * 4 + quad];
                afrag[s][k] = __builtin_bit_cast(bf16x8, v);
            }
        }

        // row labels for this lane's C rows: row = rowBase + s*16 + quad*4 + e
        int rlab[2][4];
        #pragma unroll
        for (int s = 0; s < 2; ++s)
            #pragma unroll
            for (int e = 0; e < 4; ++e)
                rlab[s][e] = labels[rowBase + s * 16 + quad * 4 + e];

        float gmax[2][4];
        #pragma unroll
        for (int s = 0; s < 2; ++s)
            #pragma unroll
            for (int e = 0; e < 4; ++e)
                gmax[s][e] = -4.0f;

        #pragma unroll
        for (int t = 0; t < 4; ++t) {         // four 32-col tiles from LDS
            bf16x8 bfrag[2][4];
            #pragma unroll
            for (int ns = 0; ns < 2; ++ns) {
                int c = t * 32 + ns * 16 + l15;
                #pragma unroll
                for (int k = 0; k < 4; ++k) {
                    int g = c * 16 + k * 4 + quad;
                    bfrag[ns][k] = __builtin_bit_cast(bf16x8, smem[swz(g)]);
                }
            }

            #pragma unroll
            for (int ms = 0; ms < 2; ++ms) {
                #pragma unroll
                for (int ns = 0; ns < 2; ++ns) {
                    floatx4 acc = {0.f, 0.f, 0.f, 0.f};
                    #pragma unroll
                    for (int k = 0; k < 4; ++k)
                        acc = __builtin_amdgcn_mfma_f32_16x16x32_bf16(
                                  afrag[ms][k], bfrag[ns][k], acc, 0, 0, 0);
                    const int cl = ns ? clab1[t] : clab0[t];
                    #pragma unroll
                    for (int e = 0; e < 4; ++e) {
                        float v = (cl != rlab[ms][e]) ? acc[e] : -4.0f;
                        gmax[ms][e] = fmaxf(gmax[ms][e], v);
                    }
                }
            }
        }

        // reduce cols over the 16 lanes of each quad, then atomicMax per row
        #pragma unroll
        for (int s = 0; s < 2; ++s) {
            #pragma unroll
            for (int e = 0; e < 4; ++e) {
                float v = gmax[s][e];
                #pragma unroll
                for (int off = 1; off < 16; off <<= 1)
                    v = fmaxf(v, __shfl_xor(v, off));
                if (l15 == 0) {
                    int r = rowBase + s * 16 + quad * 4 + e;
                    atomicMax(g_ws + r, __float_as_int(2.0f + v));  // keys > 0
                }
            }
        }
    }
}

// ---------- kernel 3: final loss + mean ----------
__global__ __launch_bounds__(256) void loss_kernel(
    const float* __restrict__ pos_ws, const int* __restrict__ g_ws,
    float* __restrict__ out)
{
    const int i = blockIdx.x * 256 + threadIdx.x;
    float g    = __int_as_float(g_ws[i]) - 2.0f;
    float neg  = fmaxf(2.0f - 2.0f * g, 0.0f);
    float loss = fmaxf(pos_ws[i] - neg + 0.5f, 0.0f);

    #pragma unroll
    for (int off = 32; off; off >>= 1)
        loss += __shfl_xor(loss, off);

    __shared__ float ws[4];
    if ((threadIdx.x & 63) == 0) ws[threadIdx.x >> 6] = loss;
    __syncthreads();
    if (threadIdx.x == 0) {
        float s = ws[0] + ws[1] + ws[2] + ws[3];
        atomicAdd(out, s * (1.0f / 8192.0f));
    }
}

extern "C" void kernel_launch(void* const* d_in, const int* in_sizes, int n_in,
                              void* d_out, int out_size, void* d_ws, size_t ws_size,
                              hipStream_t stream) {
    const float* anchor   = (const float*)d_in[0];
    const float* positive = (const float*)d_in[1];
    const int*   labels   = (const int*)d_in[2];
    float* out = (float*)d_out;

    char* ws = (char*)d_ws;
    unsigned short* a_hat  = (unsigned short*)ws;                       // 2 MiB
    float*          pos_ws = (float*)(ws + 2 * 1024 * 1024);            // 32 KiB
    int*            g_ws   = (int*)  (ws + 2 * 1024 * 1024 + 32 * 1024);// 32 KiB

    hipMemsetAsync(d_out, 0, sizeof(float), stream);
    normalize_kernel<<<NROWS / 4, 256, 0, stream>>>(anchor, positive, a_hat, pos_ws, g_ws);
    gram_kernel<<<1024, 256, 0, stream>>>(a_hat, labels, g_ws);
    loss_kernel<<<NROWS / 256, 256, 0, stream>>>(pos_ws, g_ws, out);
}